// Round 2
// baseline (745.496 us; speedup 1.0000x reference)
//
#include <hip/hip_runtime.h>
#include <float.h>

// Problem constants
#define N_TOK   32768      // B*H*W = 32*32*32
#define DIM     64
#define K_CODES 8192
#define HWSZ    1024       // H*W
#define CHW     65536      // C*H*W
#define NELEM   2097152    // B*C*H*W

// d_out layout (floats):
// [0, 2097152)                z_q_st (NCHW)
// [2097152]                   loss
// [2097153, +32768)           idx (as float)
// [2129921, +8192)            cs_norm        (doubles as cnt accumulator)
// [2138113, +524288)          ema_w_out
// [2662401, +524288)          emb_out        (doubles as new_ema_w accumulator)

// ---------------- K1: per-code squared norms ----------------
__global__ __launch_bounds__(256) void enorm_kernel(const float* __restrict__ emb,
                                                    float* __restrict__ enorm) {
    int wave = (blockIdx.x * blockDim.x + threadIdx.x) >> 6;
    int lane = threadIdx.x & 63;
    if (wave >= K_CODES) return;
    float v = emb[wave * DIM + lane];
    float s = v * v;
    #pragma unroll
    for (int m = 32; m >= 1; m >>= 1) s += __shfl_xor(s, m, 64);
    if (lane == 0) enorm[wave] = s;
}

// ---------------- K2: argmin (K-split x3, atomicMin merge) ----------------
// 64 tokens per block, tiles of 128 codes, 256 threads, 4x8 micro-tile.
// grid = 512 token-blocks * 3 K-splits = 1536 blocks -> 2 rounds of 768 (3/CU).
__global__ __launch_bounds__(256, 3) void vq_argmin(const float* __restrict__ z,
                                                    const float* __restrict__ emb,
                                                    const float* __restrict__ enorm,
                                                    unsigned long long* __restrict__ packed) {
    __shared__ float z_s[DIM * 64];     // [d][t]  16 KB
    __shared__ float e_s[DIM * 128];    // [d][k]  32 KB (reused for reduction)
    __shared__ float enorm_s[128];

    const int tid = threadIdx.x;
    const int tb  = blockIdx.x & 511;          // token-tile id
    const int ks  = blockIdx.x >> 9;           // K-split id 0..2
    const int n0  = tb * 64;
    const int zbase = (n0 >> 10) * CHW + (n0 & 1023);

    // Stage z tile: global [c][hw contiguous] -> LDS [c][t], float4 coalesced.
    {
        int f4 = tid & 15, c0 = tid >> 4;
        #pragma unroll
        for (int r = 0; r < 4; ++r) {
            int c = c0 + 16 * r;
            float4 v = *(const float4*)(z + zbase + c * HWSZ + f4 * 4);
            *(float4*)(&z_s[c * 64 + f4 * 4]) = v;
        }
    }

    // K-tile range for this split (64 tiles total -> 22/21/21)
    const int t0 = (ks == 0) ? 0 : (ks == 1 ? 22 : 43);
    const int t1 = (ks == 0) ? 22 : (ks == 1 ? 43 : 64);

    const int k_local = tid >> 1, half = tid & 1;
    float4 pf[8];
    float  pfn = 0.f;

    // prefetch tile t0
    {
        const float* src = emb + (t0 * 128 + k_local) * DIM + half * 32;
        #pragma unroll
        for (int j = 0; j < 8; ++j) pf[j] = *(const float4*)(src + j * 4);
        if (tid < 128) pfn = enorm[t0 * 128 + tid];
    }

    const int tx = tid & 15;   // code group
    const int ty = tid >> 4;   // token group (4 tokens)

    float minv[4];
    int   mini[4];
    #pragma unroll
    for (int i = 0; i < 4; ++i) { minv[i] = FLT_MAX; mini[i] = 0; }

    for (int kt = t0; kt < t1; ++kt) {
        __syncthreads();  // e_s readers done (covers z staging at first iter)
        // regs -> LDS (e tile transposed [d][k])
        #pragma unroll
        for (int j = 0; j < 8; ++j) {
            int d = half * 32 + j * 4;
            e_s[(d + 0) * 128 + k_local] = pf[j].x;
            e_s[(d + 1) * 128 + k_local] = pf[j].y;
            e_s[(d + 2) * 128 + k_local] = pf[j].z;
            e_s[(d + 3) * 128 + k_local] = pf[j].w;
        }
        if (tid < 128) enorm_s[tid] = pfn;
        // prefetch next tile into regs (overlaps compute below)
        if (kt + 1 < t1) {
            const float* src = emb + ((kt + 1) * 128 + k_local) * DIM + half * 32;
            #pragma unroll
            for (int j = 0; j < 8; ++j) pf[j] = *(const float4*)(src + j * 4);
            if (tid < 128) pfn = enorm[(kt + 1) * 128 + tid];
        }
        __syncthreads();

        float acc[4][8];
        #pragma unroll
        for (int i = 0; i < 4; ++i)
            #pragma unroll
            for (int j = 0; j < 8; ++j) acc[i][j] = 0.f;

        #pragma unroll 8
        for (int d = 0; d < DIM; ++d) {
            float4 zv = *(const float4*)(&z_s[d * 64 + ty * 4]);
            float4 ea = *(const float4*)(&e_s[d * 128 + tx * 4]);        // codes tx*4..+3
            float4 eb = *(const float4*)(&e_s[d * 128 + 64 + tx * 4]);   // codes 64+tx*4..+3
            float zr[4] = {zv.x, zv.y, zv.z, zv.w};
            float er[8] = {ea.x, ea.y, ea.z, ea.w, eb.x, eb.y, eb.z, eb.w};
            #pragma unroll
            for (int i = 0; i < 4; ++i)
                #pragma unroll
                for (int j = 0; j < 8; ++j) acc[i][j] = fmaf(zr[i], er[j], acc[i][j]);
        }

        // score = ||e||^2 - 2 z.e ; strict < keeps first index (k ascending per thread)
        const int k0 = kt * 128;
        #pragma unroll
        for (int j = 0; j < 8; ++j) {
            int kl = (j < 4) ? (tx * 4 + j) : (64 + tx * 4 + (j - 4));
            float en = enorm_s[kl];
            int k = k0 + kl;
            #pragma unroll
            for (int i = 0; i < 4; ++i) {
                float s = fmaf(-2.f, acc[i][j], en);
                if (s < minv[i]) { minv[i] = s; mini[i] = k; }
            }
        }
    }

    // Cross-thread (over tx) reduction via LDS overlaid on e_s.
    __syncthreads();
    float* red_val = e_s;                       // 1024 floats
    int*   red_idx = (int*)(e_s + 1024);        // 1024 ints
    #pragma unroll
    for (int i = 0; i < 4; ++i) {
        int t = ty * 4 + i;
        red_val[t * 16 + tx] = minv[i];
        red_idx[t * 16 + tx] = mini[i];
    }
    __syncthreads();
    if (tid < 64) {
        int base = tid * 16;
        float bv = red_val[base];
        int   bi = red_idx[base];
        #pragma unroll
        for (int x = 1; x < 16; ++x) {
            float v = red_val[base + x];
            int  ii = red_idx[base + x];
            if (v < bv || (v == bv && ii < bi)) { bv = v; bi = ii; }
        }
        // pack (monotonic float bits << 32) | idx, merge across K-splits
        unsigned ub = __float_as_uint(bv);
        ub = (ub & 0x80000000u) ? ~ub : (ub | 0x80000000u);
        unsigned long long pv = ((unsigned long long)ub << 32) | (unsigned)bi;
        atomicMin(&packed[n0 + tid], pv);
    }
}

// ---------------- K3: epilogue — gather z_q, z_q_st, loss, EMA scatter ----------------
__global__ __launch_bounds__(256) void vq_epilogue(const float* __restrict__ z,
                                                   const float* __restrict__ emb,
                                                   const unsigned long long* __restrict__ packed,
                                                   float* __restrict__ zq_out,
                                                   float* __restrict__ idx_out,
                                                   float* __restrict__ cnt,
                                                   float* __restrict__ new_ema,
                                                   float* __restrict__ loss_sum) {
    const int tid  = threadIdx.x;
    const int n0   = blockIdx.x * 64;
    const int tloc = tid & 63, cg = tid >> 6;
    const int n = n0 + tloc;
    const int myidx = (int)(packed[n] & 0xFFFFFFFFull);
    if (tid < 64) {
        idx_out[n] = (float)myidx;
        atomicAdd(&cnt[myidx], 1.0f);
    }
    const int b = n >> 10, hw = n & 1023;
    const float* erow = emb + myidx * DIM;
    const float* zrow = z + b * CHW + hw;
    float* orow = zq_out + b * CHW + hw;
    float* nrow = new_ema + myidx * DIM;
    float lsum = 0.f;
    #pragma unroll
    for (int j = 0; j < 16; ++j) {
        int c = cg * 16 + j;
        float zq = erow[c];
        float zv = zrow[c * HWSZ];
        float dd = zq - zv;
        orow[c * HWSZ] = zv + dd;       // z + (z_q - z), matches reference rounding
        lsum += dd * dd;
        atomicAdd(&nrow[c], zv);
    }
    #pragma unroll
    for (int m = 32; m >= 1; m >>= 1) lsum += __shfl_xor(lsum, m, 64);
    if ((tid & 63) == 0) atomicAdd(loss_sum, lsum);
}

// ---------------- K4: cs = decay*cluster_size + (1-decay)*cnt, and sum(cs) ----------------
__global__ __launch_bounds__(256) void cs_kernel(const float* __restrict__ cluster_size,
                                                 const float* __restrict__ cnt,
                                                 float* __restrict__ cs,
                                                 float* __restrict__ cs_sum) {
    int k = blockIdx.x * 256 + threadIdx.x;
    float v = 0.99f * cluster_size[k] + 0.01f * cnt[k];
    cs[k] = v;
    float s = v;
    #pragma unroll
    for (int m = 32; m >= 1; m >>= 1) s += __shfl_xor(s, m, 64);
    __shared__ float wsum[4];
    int lane = threadIdx.x & 63, wid = threadIdx.x >> 6;
    if (lane == 0) wsum[wid] = s;
    __syncthreads();
    if (threadIdx.x == 0) atomicAdd(cs_sum, wsum[0] + wsum[1] + wsum[2] + wsum[3]);
}

// ---------------- K5: finalize cs_norm, ema_w_out, emb_out, loss ----------------
__global__ __launch_bounds__(256) void final_kernel(const float* __restrict__ ema_w,
                                                    const float* __restrict__ cs,
                                                    const float* __restrict__ cs_sum,
                                                    const float* __restrict__ loss_sum,
                                                    float* __restrict__ csn_out,
                                                    float* __restrict__ emao_out,
                                                    float* __restrict__ embo_out,  // new_ema in, emb_out out
                                                    float* __restrict__ loss_out) {
    int g = blockIdx.x * 256 + threadIdx.x;   // 0..524287
    float denom = *cs_sum + (float)(K_CODES * 1e-5);
    int k = g >> 6;
    float csn = (cs[k] + 1e-5f) / denom;
    float ne = embo_out[g];                    // accumulated new_ema_w
    float eo = 0.99f * ema_w[g] + 0.01f * ne;
    emao_out[g] = eo;
    embo_out[g] = eo / csn;
    if (g < K_CODES) csn_out[g] = (cs[g] + 1e-5f) / denom;
    if (g == 0) *loss_out = 0.25f * (*loss_sum) * (1.0f / (float)NELEM);
}

extern "C" void kernel_launch(void* const* d_in, const int* in_sizes, int n_in,
                              void* d_out, int out_size, void* d_ws, size_t ws_size,
                              hipStream_t stream) {
    (void)in_sizes; (void)n_in; (void)out_size; (void)ws_size;
    const float* z      = (const float*)d_in[0];
    const float* emb    = (const float*)d_in[1];
    const float* ema_w  = (const float*)d_in[2];
    const float* csize  = (const float*)d_in[3];

    float* out      = (float*)d_out;
    float* zq_out   = out;
    float* loss_out = out + 2097152;
    float* idx_out  = out + 2097153;
    float* csn_out  = out + 2129921;   // cnt accumulator, then cs_norm
    float* emao_out = out + 2138113;
    float* embo_out = out + 2662401;   // new_ema accumulator, then emb_out

    float* ws       = (float*)d_ws;
    float* enorm    = ws;                                  // 8192 floats
    unsigned long long* packed = (unsigned long long*)(ws + 8192);  // 32768 u64
    float* cs       = ws + 8192 + 65536;                   // 8192 floats
    float* cs_sum   = cs + 8192;                           // 1
    float* loss_sum = cs + 8193;                           // 1

    hipMemsetAsync(packed, 0xFF, N_TOK * sizeof(unsigned long long), stream);
    hipMemsetAsync(csn_out, 0, K_CODES * sizeof(float), stream);
    hipMemsetAsync(embo_out, 0, K_CODES * DIM * sizeof(float), stream);
    hipMemsetAsync(cs_sum, 0, 2 * sizeof(float), stream);

    enorm_kernel<<<K_CODES * 64 / 256, 256, 0, stream>>>(emb, enorm);
    vq_argmin<<<1536, 256, 0, stream>>>(z, emb, enorm, packed);
    vq_epilogue<<<N_TOK / 64, 256, 0, stream>>>(z, emb, packed, zq_out, idx_out,
                                                csn_out, embo_out, loss_sum);
    cs_kernel<<<K_CODES / 256, 256, 0, stream>>>(csize, csn_out, cs, cs_sum);
    final_kernel<<<K_CODES * DIM / 256, 256, 0, stream>>>(ema_w, cs, cs_sum, loss_sum,
                                                          csn_out, emao_out, embo_out, loss_out);
}

// Round 3
// 359.058 us; speedup vs baseline: 2.0763x; 2.0763x over previous
//
#include <hip/hip_runtime.h>
#include <float.h>

#define N_TOK   32768
#define DIM     64
#define K_CODES 8192
#define HWSZ    1024
#define CHW     65536
#define NELEM   2097152

typedef short  bf16x8 __attribute__((ext_vector_type(8)));
typedef float  f32x16 __attribute__((ext_vector_type(16)));

static __device__ __forceinline__ unsigned short f2bf(float x) {
    unsigned u = __float_as_uint(x);
    unsigned r = u + 0x7FFFu + ((u >> 16) & 1u);
    return (unsigned short)(r >> 16);
}
static __device__ __forceinline__ float bf2f(unsigned short h) {
    return __uint_as_float(((unsigned)h) << 16);
}

// ---------------- prep_e: emb -> frag-ordered bf16 hi/lo blob ----------------
// blob layout (ushorts): tile(128)*8192 + ((s*2+p)*2+h)*512 + n*8
// chunk (s,p,h,n) = e_p[tile*64+n][s*16+h*8 .. +8]
__global__ __launch_bounds__(256) void prep_e(const float* __restrict__ emb,
                                              unsigned short* __restrict__ blob) {
    int tile = blockIdx.x;
    #pragma unroll
    for (int u0 = 0; u0 < 2; ++u0) {
        int u = threadIdx.x + u0 * 256;
        int s = u >> 7, h = (u >> 6) & 1, n = u & 63;
        const float* src = emb + (tile * 64 + n) * 64 + s * 16 + h * 8;
        float4 v0 = *(const float4*)src;
        float4 v1 = *(const float4*)(src + 4);
        float x[8] = {v0.x, v0.y, v0.z, v0.w, v1.x, v1.y, v1.z, v1.w};
        unsigned short hi[8], lo[8];
        #pragma unroll
        for (int j = 0; j < 8; ++j) {
            hi[j] = f2bf(x[j]);
            lo[j] = f2bf(x[j] - bf2f(hi[j]));
        }
        unsigned short* dhi = blob + (size_t)tile * 8192 + ((s * 2 + 0) * 2 + h) * 512 + n * 8;
        unsigned short* dlo = blob + (size_t)tile * 8192 + ((s * 2 + 1) * 2 + h) * 512 + n * 8;
        uint4 ph, pl;
        ph.x = (unsigned)hi[0] | ((unsigned)hi[1] << 16);
        ph.y = (unsigned)hi[2] | ((unsigned)hi[3] << 16);
        ph.z = (unsigned)hi[4] | ((unsigned)hi[5] << 16);
        ph.w = (unsigned)hi[6] | ((unsigned)hi[7] << 16);
        pl.x = (unsigned)lo[0] | ((unsigned)lo[1] << 16);
        pl.y = (unsigned)lo[2] | ((unsigned)lo[3] << 16);
        pl.z = (unsigned)lo[4] | ((unsigned)lo[5] << 16);
        pl.w = (unsigned)lo[6] | ((unsigned)lo[7] << 16);
        *(uint4*)dhi = ph;
        *(uint4*)dlo = pl;
    }
}

// ---------------- enorm: eng[k] = ||e_k||^2 (fp32 exact) ----------------
__global__ __launch_bounds__(256) void enorm_kernel(const float* __restrict__ emb,
                                                    float* __restrict__ eng) {
    int wave = (blockIdx.x * blockDim.x + threadIdx.x) >> 6;
    int lane = threadIdx.x & 63;
    if (wave >= K_CODES) return;
    float v = emb[wave * DIM + lane];
    float s = v * v;
    #pragma unroll
    for (int m = 32; m >= 1; m >>= 1) s += __shfl_xor(s, m, 64);
    if (lane == 0) eng[wave] = s;
}

// ---------------- argmin: MFMA bf16x3, 128 tok x 64 codes/block, K-split x2 ----
__global__ __launch_bounds__(256, 2) void vq_argmin(const float* __restrict__ z,
                                                    const unsigned short* __restrict__ blob,
                                                    const float* __restrict__ eng,
                                                    unsigned long long* __restrict__ packed) {
    __shared__ unsigned short zh[128 * 72];   // padded rows (144 B, 16B-aligned)
    __shared__ unsigned short zl[128 * 72];
    __shared__ unsigned short bbuf[2 * 8192]; // double-buffered 16 KB tiles
    __shared__ unsigned long long red[128 * 2];

    const int tid  = threadIdx.x;
    const int lane = tid & 63;
    const int wid  = tid >> 6;
    const int wr   = wid >> 1, wc = wid & 1;
    const int l31  = lane & 31, h = lane >> 5;

    const int tb = blockIdx.x & 255;
    const int ks = blockIdx.x >> 8;
    const int n0 = tb * 128;
    const int zbase = (n0 >> 10) * CHW + (n0 & 1023);
    const int t0 = ks * 64, t1 = t0 + 64;

    // ---- stage z tile (NCHW -> LDS [t][k] bf16 hi/lo, rows padded to 72) ----
    {
        int f4 = tid & 31;       // hw chunk (4 tokens)
        int c0 = tid >> 5;       // 0..7
        #pragma unroll
        for (int r = 0; r < 8; ++r) {
            int c = c0 * 8 + r;
            float4 v = *(const float4*)(z + zbase + c * HWSZ + f4 * 4);
            float x[4] = {v.x, v.y, v.z, v.w};
            #pragma unroll
            for (int e = 0; e < 4; ++e) {
                int t = f4 * 4 + e;
                unsigned short hi = f2bf(x[e]);
                zh[t * 72 + c] = hi;
                zl[t * 72 + c] = f2bf(x[e] - bf2f(hi));
            }
        }
    }

    // ---- prefetch first B tile into regs ----
    uint4 pf[4];
    {
        const unsigned short* gsrc = blob + (size_t)t0 * 8192;
        #pragma unroll
        for (int c = 0; c < 4; ++c) {
            int ch = wid * 4 + c;
            pf[c] = *(const uint4*)(gsrc + ch * 512 + lane * 8);
        }
    }

    __syncthreads();   // z visible

    // ---- A-fragments (z) into registers: [mt][s][p] ----
    bf16x8 Af[2][4][2];
    #pragma unroll
    for (int mt = 0; mt < 2; ++mt) {
        int row = wr * 64 + mt * 32 + l31;
        #pragma unroll
        for (int s = 0; s < 4; ++s) {
            Af[mt][s][0] = *(const bf16x8*)(&zh[row * 72 + s * 16 + h * 8]);
            Af[mt][s][1] = *(const bf16x8*)(&zl[row * 72 + s * 16 + h * 8]);
        }
    }

    // write first tile to buf0
    #pragma unroll
    for (int c = 0; c < 4; ++c) {
        int ch = wid * 4 + c;
        *(uint4*)(&bbuf[ch * 512 + lane * 8]) = pf[c];
    }
    __syncthreads();   // buf0 visible

    float minv0[16], minv1[16];
    int   mini0[16], mini1[16];
    #pragma unroll
    for (int r = 0; r < 16; ++r) {
        minv0[r] = FLT_MAX; minv1[r] = FLT_MAX;
        mini0[r] = 0;       mini1[r] = 0;
    }

    int cur = 0;
    for (int kt = t0; kt < t1; ++kt) {
        bool hn = (kt + 1 < t1);
        if (hn) {
            const unsigned short* gsrc = blob + (size_t)(kt + 1) * 8192;
            #pragma unroll
            for (int c = 0; c < 4; ++c) {
                int ch = wid * 4 + c;
                pf[c] = *(const uint4*)(gsrc + ch * 512 + lane * 8);
            }
        }
        float en = eng[kt * 64 + wc * 32 + l31];
        int  col = kt * 64 + wc * 32 + l31;

        const unsigned short* bb = bbuf + cur * 8192;
        f32x16 ac0, ac1;
        #pragma unroll
        for (int r = 0; r < 16; ++r) { ac0[r] = 0.f; ac1[r] = 0.f; }

        #pragma unroll
        for (int s = 0; s < 4; ++s) {
            bf16x8 bh = *(const bf16x8*)(&bb[((s * 2 + 0) * 2 + h) * 512 + (wc * 32 + l31) * 8]);
            bf16x8 bl = *(const bf16x8*)(&bb[((s * 2 + 1) * 2 + h) * 512 + (wc * 32 + l31) * 8]);
            ac0 = __builtin_amdgcn_mfma_f32_32x32x16_bf16(Af[0][s][1], bh, ac0, 0, 0, 0);
            ac0 = __builtin_amdgcn_mfma_f32_32x32x16_bf16(Af[0][s][0], bl, ac0, 0, 0, 0);
            ac0 = __builtin_amdgcn_mfma_f32_32x32x16_bf16(Af[0][s][0], bh, ac0, 0, 0, 0);
            ac1 = __builtin_amdgcn_mfma_f32_32x32x16_bf16(Af[1][s][1], bh, ac1, 0, 0, 0);
            ac1 = __builtin_amdgcn_mfma_f32_32x32x16_bf16(Af[1][s][0], bl, ac1, 0, 0, 0);
            ac1 = __builtin_amdgcn_mfma_f32_32x32x16_bf16(Af[1][s][0], bh, ac1, 0, 0, 0);
        }

        #pragma unroll
        for (int r = 0; r < 16; ++r) {
            float d0 = fmaf(-2.f, ac0[r], en);
            if (d0 < minv0[r]) { minv0[r] = d0; mini0[r] = col; }
            float d1 = fmaf(-2.f, ac1[r], en);
            if (d1 < minv1[r]) { minv1[r] = d1; mini1[r] = col; }
        }

        if (hn) {
            #pragma unroll
            for (int c = 0; c < 4; ++c) {
                int ch = wid * 4 + c;
                *(uint4*)(&bbuf[(cur ^ 1) * 8192 + ch * 512 + lane * 8]) = pf[c];
            }
        }
        __syncthreads();
        cur ^= 1;
    }

    // ---- reduction: pack (mono<<32|idx), 5-step butterfly over 32 cols ----
    #pragma unroll
    for (int mt = 0; mt < 2; ++mt) {
        unsigned long long pv[16];
        #pragma unroll
        for (int r = 0; r < 16; ++r) {
            float v = mt ? minv1[r] : minv0[r];
            int   i = mt ? mini1[r] : mini0[r];
            unsigned u = __float_as_uint(v);
            u = (u & 0x80000000u) ? ~u : (u | 0x80000000u);
            pv[r] = ((unsigned long long)u << 32) | (unsigned)i;
        }
        #pragma unroll
        for (int m = 1; m <= 16; m <<= 1) {
            #pragma unroll
            for (int r = 0; r < 16; ++r) {
                unsigned long long o = __shfl_xor(pv[r], m, 64);
                if (o < pv[r]) pv[r] = o;
            }
        }
        #pragma unroll
        for (int r = 0; r < 16; ++r) {
            if (l31 == r) {
                int row = wr * 64 + mt * 32 + (r & 3) + 8 * (r >> 2) + 4 * h;
                red[row * 2 + wc] = pv[r];
            }
        }
    }
    __syncthreads();
    if (tid < 128) {
        unsigned long long a = red[tid * 2], b = red[tid * 2 + 1];
        unsigned long long m = (b < a) ? b : a;
        atomicMin(&packed[n0 + tid], m);
    }
}

// ---------------- zq_loss: idx out, cnt histogram, z_q_st, loss ----------------
__global__ __launch_bounds__(256) void zq_loss(const float* __restrict__ z,
                                               const float* __restrict__ emb,
                                               const unsigned long long* __restrict__ packed,
                                               float* __restrict__ zq_out,
                                               float* __restrict__ idx_out,
                                               int* __restrict__ idx_i32,
                                               int* __restrict__ cnt_i,
                                               float* __restrict__ loss_sum) {
    const int tid = threadIdx.x;
    const int n0  = blockIdx.x * 64;
    const int t   = tid >> 2, q = tid & 3;
    const int n   = n0 + t;
    const int idx = (int)(packed[n] & 0xFFFFFFFFull);
    if (q == 0) {
        idx_out[n] = (float)idx;
        idx_i32[n] = idx;
        atomicAdd(&cnt_i[idx], 1);
    }
    const int b = n >> 10, hw = n & 1023;
    const float* er = emb + idx * 64 + q * 16;
    float4 e0 = *(const float4*)er, e1 = *(const float4*)(er + 4);
    float4 e2 = *(const float4*)(er + 8), e3 = *(const float4*)(er + 12);
    float ev[16] = {e0.x, e0.y, e0.z, e0.w, e1.x, e1.y, e1.z, e1.w,
                    e2.x, e2.y, e2.z, e2.w, e3.x, e3.y, e3.z, e3.w};
    float lsum = 0.f;
    #pragma unroll
    for (int j = 0; j < 16; ++j) {
        int c = q * 16 + j;
        float zv = z[b * CHW + c * HWSZ + hw];
        float dd = ev[j] - zv;
        zq_out[b * CHW + c * HWSZ + hw] = zv + dd;
        lsum += dd * dd;
    }
    #pragma unroll
    for (int m = 32; m >= 1; m >>= 1) lsum += __shfl_xor(lsum, m, 64);
    if ((tid & 63) == 0) atomicAdd(loss_sum, lsum);
}

// ---------------- scan: exclusive prefix over cnt_i -> offsets, cursor ----------
__global__ __launch_bounds__(1024) void scan_kernel(const int* __restrict__ cnt_i,
                                                    int* __restrict__ offsets,
                                                    int* __restrict__ cursor) {
    __shared__ int sc[1024];
    const int tid = threadIdx.x;
    int v[8], part = 0;
    #pragma unroll
    for (int j = 0; j < 8; ++j) { v[j] = cnt_i[tid * 8 + j]; part += v[j]; }
    sc[tid] = part;
    __syncthreads();
    for (int off = 1; off < 1024; off <<= 1) {
        int add = (tid >= off) ? sc[tid - off] : 0;
        __syncthreads();
        sc[tid] += add;
        __syncthreads();
    }
    int run = sc[tid] - part;
    #pragma unroll
    for (int j = 0; j < 8; ++j) {
        offsets[tid * 8 + j] = run;
        cursor[tid * 8 + j]  = run;
        run += v[j];
    }
}

// ---------------- scatter tokens into code-sorted order ----------------
__global__ __launch_bounds__(256) void scatter_kernel(const int* __restrict__ idx_i32,
                                                      int* __restrict__ cursor,
                                                      int* __restrict__ tok_of) {
    int t = blockIdx.x * 256 + threadIdx.x;
    int k = idx_i32[t];
    int pos = atomicAdd(&cursor[k], 1);
    tok_of[pos] = t;
}

// ---------------- cs = decay*cluster_size + (1-decay)*cnt; sum ----------------
__global__ __launch_bounds__(256) void cs_kernel(const float* __restrict__ cluster_size,
                                                 const int* __restrict__ cnt_i,
                                                 float* __restrict__ cs,
                                                 float* __restrict__ cs_sum) {
    int k = blockIdx.x * 256 + threadIdx.x;
    float v = 0.99f * cluster_size[k] + 0.01f * (float)cnt_i[k];
    cs[k] = v;
    float s = v;
    #pragma unroll
    for (int m = 32; m >= 1; m >>= 1) s += __shfl_xor(s, m, 64);
    __shared__ float wsum[4];
    int lane = threadIdx.x & 63, w = threadIdx.x >> 6;
    if (lane == 0) wsum[w] = s;
    __syncthreads();
    if (threadIdx.x == 0) atomicAdd(cs_sum, wsum[0] + wsum[1] + wsum[2] + wsum[3]);
}

// ---------------- ema_reduce: wave per code, no float atomics ----------------
__global__ __launch_bounds__(256) void ema_reduce(const float* __restrict__ z,
                                                  const float* __restrict__ ema_w,
                                                  const int* __restrict__ offsets,
                                                  const int* __restrict__ cnt_i,
                                                  const int* __restrict__ tok_of,
                                                  float* __restrict__ emao_out) {
    const int wid = threadIdx.x >> 6, lane = threadIdx.x & 63;
    const int k = blockIdx.x * 4 + wid;
    const int o0 = offsets[k], c = cnt_i[k];
    float acc = 0.f;
    for (int i = 0; i < c; ++i) {
        int tok = tok_of[o0 + i];
        acc += z[(tok >> 10) * CHW + lane * HWSZ + (tok & 1023)];
    }
    emao_out[k * 64 + lane] = 0.99f * ema_w[k * 64 + lane] + 0.01f * acc;
}

// ---------------- final: cs_norm, emb_out, loss ----------------
__global__ __launch_bounds__(256) void final_kernel(const float* __restrict__ cs,
                                                    const float* __restrict__ cs_sum,
                                                    const float* __restrict__ loss_sum,
                                                    const float* __restrict__ emao_out,
                                                    float* __restrict__ csn_out,
                                                    float* __restrict__ embo_out,
                                                    float* __restrict__ loss_out) {
    int g = blockIdx.x * 256 + threadIdx.x;
    float denom = *cs_sum + (float)(K_CODES * 1e-5);
    int k = g >> 6;
    float csn = (cs[k] + 1e-5f) / denom;
    embo_out[g] = emao_out[g] / csn;
    if (g < K_CODES) csn_out[g] = (cs[g] + 1e-5f) / denom;
    if (g == 0) *loss_out = 0.25f * (*loss_sum) * (1.0f / (float)NELEM);
}

extern "C" void kernel_launch(void* const* d_in, const int* in_sizes, int n_in,
                              void* d_out, int out_size, void* d_ws, size_t ws_size,
                              hipStream_t stream) {
    (void)in_sizes; (void)n_in; (void)out_size; (void)ws_size;
    const float* z     = (const float*)d_in[0];
    const float* emb   = (const float*)d_in[1];
    const float* ema_w = (const float*)d_in[2];
    const float* csize = (const float*)d_in[3];

    float* out      = (float*)d_out;
    float* zq_out   = out;
    float* loss_out = out + 2097152;
    float* idx_out  = out + 2097153;
    float* csn_out  = out + 2129921;
    float* emao_out = out + 2138113;
    float* embo_out = out + 2662401;

    char* wsb = (char*)d_ws;
    unsigned short*     blob     = (unsigned short*)(wsb);             // 2 MB
    float*              eng      = (float*)(wsb + 2097152);            // 32 KB
    float*              cs       = (float*)(wsb + 2129920);            // 32 KB
    float*              cs_sum   = (float*)(wsb + 2162688);            // 4 B
    float*              loss_sum = (float*)(wsb + 2162692);            // 4 B
    unsigned long long* packed   = (unsigned long long*)(wsb + 2162696); // 256 KB
    int*                idx_i32  = (int*)(wsb + 2424840);              // 128 KB
    int*                cnt_i    = (int*)(wsb + 2555912);              // 32 KB
    int*                offsets  = (int*)(wsb + 2588680);              // 32 KB
    int*                cursor   = (int*)(wsb + 2621448);              // 32 KB
    int*                tok_of   = (int*)(wsb + 2654216);              // 128 KB

    hipMemsetAsync(packed, 0xFF, N_TOK * sizeof(unsigned long long), stream);
    hipMemsetAsync(cnt_i, 0, K_CODES * sizeof(int), stream);
    hipMemsetAsync(cs_sum, 0, 8, stream);   // cs_sum + loss_sum

    prep_e<<<128, 256, 0, stream>>>(emb, blob);
    enorm_kernel<<<K_CODES * 64 / 256, 256, 0, stream>>>(emb, eng);
    vq_argmin<<<512, 256, 0, stream>>>(z, blob, eng, packed);
    zq_loss<<<N_TOK / 64, 256, 0, stream>>>(z, emb, packed, zq_out, idx_out,
                                            idx_i32, cnt_i, loss_sum);
    scan_kernel<<<1, 1024, 0, stream>>>(cnt_i, offsets, cursor);
    scatter_kernel<<<N_TOK / 256, 256, 0, stream>>>(idx_i32, cursor, tok_of);
    cs_kernel<<<K_CODES / 256, 256, 0, stream>>>(csize, cnt_i, cs, cs_sum);
    ema_reduce<<<K_CODES / 4 / 256 * 256, 256, 0, stream>>>(z, ema_w, offsets, cnt_i,
                                                            tok_of, emao_out);
    final_kernel<<<K_CODES * DIM / 256, 256, 0, stream>>>(cs, cs_sum, loss_sum, emao_out,
                                                          csn_out, embo_out, loss_out);
}